// Round 1
// baseline (324.499 us; speedup 1.0000x reference)
//
#include <hip/hip_runtime.h>

// GroupDRO loss: per-sample 3-class CE, group = mean(logits)<0.4 ? 0 : 1,
// subgroup = group*3 + label. Only 6 subgroup sums are needed; group sums,
// total CE, and combined loss derive from them in the finalize kernel.
//
// R2 -> R3: rocprof showed dro_partial at ~3.3 TB/s (~80 us) while harness
// poison-fills hit 6.8 TB/s on the same chip. Cause: GRID=1024 caps occupancy
// at 4 blocks/CU (16/32 waves) and the unrolled body serializes load->compute.
// Fix: GRID=2048 (8 blocks/CU) + explicit depth-1 prefetch pipeline so each
// wave always has 64 B of loads in flight while computing. Per-sample math is
// bit-identical to R2.

constexpr int N_SAMPLES = 16777216;
constexpr int NQ = N_SAMPLES / 4;          // 4,194,304 quad-samples
constexpr int BLOCK = 256;
constexpr int GRID = 2048;                 // 8 blocks/CU -> up to 32 waves/CU
constexpr int STRIDE = GRID * BLOCK;       // 524,288 threads
constexpr int ITERS = NQ / STRIDE;         // exactly 8, no tail
constexpr int WAVES = BLOCK / 64;

static_assert(ITERS * STRIDE == NQ, "exact tiling");

__global__ __launch_bounds__(BLOCK) void dro_partial(
    const float* __restrict__ logits,
    const int*   __restrict__ labels,
    float*       __restrict__ partials)    // [GRID][6] in d_ws (overwritten)
{
    const float4* __restrict__ lg = (const float4*)logits;
    const int4*   __restrict__ lb = (const int4*)labels;

    float acc[6] = {0.f, 0.f, 0.f, 0.f, 0.f, 0.f};
    const int base = blockIdx.x * BLOCK + threadIdx.x;

    // prologue: load iteration 0
    float4 c0 = lg[3 * base + 0];
    float4 c1 = lg[3 * base + 1];
    float4 c2 = lg[3 * base + 2];
    int4   cl = lb[base];

    #pragma unroll
    for (int it = 0; it < ITERS; ++it) {
        // issue next iteration's loads BEFORE touching current data,
        // so HBM latency hides under the softmax compute below
        float4 n0, n1, n2;
        int4   nl;
        if (it + 1 < ITERS) {
            const int q = base + (it + 1) * STRIDE;
            n0 = lg[3 * q + 0];
            n1 = lg[3 * q + 1];
            n2 = lg[3 * q + 2];
            nl = lb[q];
        }

        float xs[12] = {c0.x, c0.y, c0.z, c0.w, c1.x, c1.y,
                        c1.z, c1.w, c2.x, c2.y, c2.z, c2.w};
        int   ls[4]  = {cl.x, cl.y, cl.z, cl.w};

        #pragma unroll
        for (int s = 0; s < 4; ++s) {
            float a = xs[3 * s], b = xs[3 * s + 1], c = xs[3 * s + 2];
            int lab = ls[s];

            float m  = fmaxf(a, fmaxf(b, c));
            float ea = __expf(a - m), eb = __expf(b - m), ec = __expf(c - m);
            float lse = m + __logf(ea + eb + ec);
            float xl = (lab == 0) ? a : ((lab == 1) ? b : c);
            float ce = lse - xl;

            float mean = (a + b + c) * (1.0f / 3.0f);
            int g  = (mean < 0.4f) ? 0 : 1;
            int sg = g * 3 + lab;

            #pragma unroll
            for (int j = 0; j < 6; ++j)
                acc[j] += (j == sg) ? ce : 0.0f;   // branchless scatter
        }

        if (it + 1 < ITERS) {
            c0 = n0; c1 = n1; c2 = n2; cl = nl;
        }
    }

    // wave reduce (64 lanes)
    #pragma unroll
    for (int j = 0; j < 6; ++j) {
        #pragma unroll
        for (int off = 32; off > 0; off >>= 1)
            acc[j] += __shfl_down(acc[j], off, 64);
    }

    __shared__ float lds[WAVES][6];
    const int wave = threadIdx.x >> 6;
    const int lane = threadIdx.x & 63;
    if (lane == 0) {
        #pragma unroll
        for (int j = 0; j < 6; ++j) lds[wave][j] = acc[j];
    }
    __syncthreads();

    if (threadIdx.x < 6) {
        float s = 0.f;
        #pragma unroll
        for (int w = 0; w < WAVES; ++w) s += lds[w][threadIdx.x];
        partials[blockIdx.x * 6 + threadIdx.x] = s;  // no atomics, no pre-zero
    }
}

__global__ __launch_bounds__(BLOCK) void dro_finalize(
    const float* __restrict__ partials,    // [GRID][6]
    const float* __restrict__ gw,
    float* __restrict__ out)
{
    float acc[6] = {0.f, 0.f, 0.f, 0.f, 0.f, 0.f};
    for (int b = threadIdx.x; b < GRID; b += BLOCK) {
        #pragma unroll
        for (int j = 0; j < 6; ++j) acc[j] += partials[b * 6 + j];
    }

    #pragma unroll
    for (int j = 0; j < 6; ++j) {
        #pragma unroll
        for (int off = 32; off > 0; off >>= 1)
            acc[j] += __shfl_down(acc[j], off, 64);
    }

    __shared__ float lds[WAVES][6];
    const int wave = threadIdx.x >> 6;
    const int lane = threadIdx.x & 63;
    if (lane == 0) {
        #pragma unroll
        for (int j = 0; j < 6; ++j) lds[wave][j] = acc[j];
    }
    __syncthreads();

    if (threadIdx.x == 0) {
        float sg[6];
        float tot = 0.f;
        #pragma unroll
        for (int j = 0; j < 6; ++j) {
            float s = 0.f;
            #pragma unroll
            for (int w = 0; w < WAVES; ++w) s += lds[w][j];
            sg[j] = s;
            tot += s;
        }
        float g0 = sg[0] + sg[1] + sg[2];
        float g1 = sg[3] + sg[4] + sg[5];
        float total_loss = g0 * gw[0] + g1 * gw[1];
        float standard   = tot / (float)N_SAMPLES;
        float combined   = 0.7f * standard + 0.3f * total_loss;
        out[0] = combined;
        out[1] = g0;
        out[2] = g1;
        #pragma unroll
        for (int j = 0; j < 6; ++j) out[3 + j] = sg[j];
    }
}

extern "C" void kernel_launch(void* const* d_in, const int* in_sizes, int n_in,
                              void* d_out, int out_size, void* d_ws, size_t ws_size,
                              hipStream_t stream) {
    const float* logits = (const float*)d_in[0];
    const int*   labels = (const int*)d_in[1];
    const float* gw     = (const float*)d_in[2];
    float* partials = (float*)d_ws;    // GRID*6 floats, fully overwritten
    float* out      = (float*)d_out;   // [combined, g0, g1, sg0..sg5]

    dro_partial<<<GRID, BLOCK, 0, stream>>>(logits, labels, partials);
    dro_finalize<<<1, BLOCK, 0, stream>>>(partials, gw, out);
}

// Round 2
// 319.990 us; speedup vs baseline: 1.0141x; 1.0141x over previous
//
#include <hip/hip_runtime.h>

// GroupDRO loss: per-sample 3-class CE, group = mean(logits)<0.4 ? 0 : 1,
// subgroup = group*3 + label. Only 6 subgroup sums are needed; group sums,
// total CE, and combined loss derive from them in the finalize kernel.
//
// R3 -> R4: occupancy/prefetch (R3) was neutral -> not latency-bound. New
// theory: logits loads are dwordx4 at 48 B lane stride (each wave instr
// touches 48 x 64B segments instead of 16 -> 3x request-path work, ~3.3 TB/s).
// Fix: stage each block's 12 KiB logits tile in LDS via three perfectly
// coalesced float4 loads per thread, then read 48 B/thread from LDS.
// Per-thread quad assignment is bit-identical to R2 (quad = it*STRIDE/...
// = it*262144 + blockIdx.x*256 + tid), so partial sums match exactly.

constexpr int N_SAMPLES = 16777216;
constexpr int NQ = N_SAMPLES / 4;          // 4,194,304 quad-samples
constexpr int BLOCK = 256;
constexpr int GRID = 1024;                 // R2's best config
constexpr int ITERS = NQ / (GRID * BLOCK); // exactly 16, no tail
constexpr int WAVES = BLOCK / 64;

static_assert(ITERS * GRID * BLOCK == NQ, "exact tiling");

__global__ __launch_bounds__(BLOCK) void dro_partial(
    const float* __restrict__ logits,
    const int*   __restrict__ labels,
    float*       __restrict__ partials)    // [GRID][6] in d_ws (overwritten)
{
    const float4* __restrict__ lg4 = (const float4*)logits;
    const int4*   __restrict__ lb4 = (const int4*)labels;

    __shared__ float4 stage[3 * BLOCK];    // 768 float4 = 12 KiB logits tile

    float acc[6] = {0.f, 0.f, 0.f, 0.f, 0.f, 0.f};
    const int tid = threadIdx.x;

    for (int it = 0; it < ITERS; ++it) {
        const int blk = it * GRID + blockIdx.x;          // tile index
        const float4* __restrict__ src = lg4 + (size_t)blk * (3 * BLOCK);

        // fully coalesced: lane-consecutive float4s, 16 B/lane, zero stride gaps
        float4 v0 = src[tid];
        float4 v1 = src[tid + BLOCK];
        float4 v2 = src[tid + 2 * BLOCK];
        int4   l4 = lb4[blk * BLOCK + tid];              // already coalesced

        if (it) __syncthreads();           // prev iter's LDS reads done (WAR)
        stage[tid]             = v0;
        stage[tid + BLOCK]     = v1;
        stage[tid + 2 * BLOCK] = v2;
        __syncthreads();                   // writes visible to all lanes (RAW)

        // 48 B/thread transpose out of LDS: 3*tid+k covers all 8 bank-groups
        // in every 8 consecutive lanes -> no serializing conflicts
        float4 r0 = stage[3 * tid + 0];
        float4 r1 = stage[3 * tid + 1];
        float4 r2 = stage[3 * tid + 2];

        float xs[12] = {r0.x, r0.y, r0.z, r0.w, r1.x, r1.y,
                        r1.z, r1.w, r2.x, r2.y, r2.z, r2.w};
        int   ls[4]  = {l4.x, l4.y, l4.z, l4.w};

        #pragma unroll
        for (int s = 0; s < 4; ++s) {
            float a = xs[3 * s], b = xs[3 * s + 1], c = xs[3 * s + 2];
            int lab = ls[s];

            float m  = fmaxf(a, fmaxf(b, c));
            float ea = __expf(a - m), eb = __expf(b - m), ec = __expf(c - m);
            float lse = m + __logf(ea + eb + ec);
            float xl = (lab == 0) ? a : ((lab == 1) ? b : c);
            float ce = lse - xl;

            float mean = (a + b + c) * (1.0f / 3.0f);
            int g  = (mean < 0.4f) ? 0 : 1;
            int sg = g * 3 + lab;

            #pragma unroll
            for (int j = 0; j < 6; ++j)
                acc[j] += (j == sg) ? ce : 0.0f;   // branchless scatter
        }
    }

    // wave reduce (64 lanes)
    #pragma unroll
    for (int j = 0; j < 6; ++j) {
        #pragma unroll
        for (int off = 32; off > 0; off >>= 1)
            acc[j] += __shfl_down(acc[j], off, 64);
    }

    __shared__ float lds[WAVES][6];
    const int wave = threadIdx.x >> 6;
    const int lane = threadIdx.x & 63;
    if (lane == 0) {
        #pragma unroll
        for (int j = 0; j < 6; ++j) lds[wave][j] = acc[j];
    }
    __syncthreads();

    if (threadIdx.x < 6) {
        float s = 0.f;
        #pragma unroll
        for (int w = 0; w < WAVES; ++w) s += lds[w][threadIdx.x];
        partials[blockIdx.x * 6 + threadIdx.x] = s;  // no atomics, no pre-zero
    }
}

__global__ __launch_bounds__(BLOCK) void dro_finalize(
    const float* __restrict__ partials,    // [GRID][6]
    const float* __restrict__ gw,
    float* __restrict__ out)
{
    float acc[6] = {0.f, 0.f, 0.f, 0.f, 0.f, 0.f};
    for (int b = threadIdx.x; b < GRID; b += BLOCK) {
        #pragma unroll
        for (int j = 0; j < 6; ++j) acc[j] += partials[b * 6 + j];
    }

    #pragma unroll
    for (int j = 0; j < 6; ++j) {
        #pragma unroll
        for (int off = 32; off > 0; off >>= 1)
            acc[j] += __shfl_down(acc[j], off, 64);
    }

    __shared__ float lds[WAVES][6];
    const int wave = threadIdx.x >> 6;
    const int lane = threadIdx.x & 63;
    if (lane == 0) {
        #pragma unroll
        for (int j = 0; j < 6; ++j) lds[wave][j] = acc[j];
    }
    __syncthreads();

    if (threadIdx.x == 0) {
        float sg[6];
        float tot = 0.f;
        #pragma unroll
        for (int j = 0; j < 6; ++j) {
            float s = 0.f;
            #pragma unroll
            for (int w = 0; w < WAVES; ++w) s += lds[w][j];
            sg[j] = s;
            tot += s;
        }
        float g0 = sg[0] + sg[1] + sg[2];
        float g1 = sg[3] + sg[4] + sg[5];
        float total_loss = g0 * gw[0] + g1 * gw[1];
        float standard   = tot / (float)N_SAMPLES;
        float combined   = 0.7f * standard + 0.3f * total_loss;
        out[0] = combined;
        out[1] = g0;
        out[2] = g1;
        #pragma unroll
        for (int j = 0; j < 6; ++j) out[3 + j] = sg[j];
    }
}

extern "C" void kernel_launch(void* const* d_in, const int* in_sizes, int n_in,
                              void* d_out, int out_size, void* d_ws, size_t ws_size,
                              hipStream_t stream) {
    const float* logits = (const float*)d_in[0];
    const int*   labels = (const int*)d_in[1];
    const float* gw     = (const float*)d_in[2];
    float* partials = (float*)d_ws;    // GRID*6 floats, fully overwritten
    float* out      = (float*)d_out;   // [combined, g0, g1, sg0..sg5]

    dro_partial<<<GRID, BLOCK, 0, stream>>>(logits, labels, partials);
    dro_finalize<<<1, BLOCK, 0, stream>>>(partials, gw, out);
}